// Round 1
// 451.982 us; speedup vs baseline: 1.0450x; 1.0450x over previous
//
#include <hip/hip_runtime.h>
#include <stdint.h>

// E=8, T=4096, H=1024, I=512. fp32 I/O, bf16 MFMA compute internally.
// d_ws layout (128 MiB): w1b | w2b | w3b | w4b | h1(=h3) | h2(=xb)  (all bf16)
// xb (bf16 copy of x) aliases h2: dead before GEMM2 writes h2.

#define BM 128
#define BN 128
#define BK 64

typedef __attribute__((ext_vector_type(8))) short short8;
typedef __attribute__((ext_vector_type(4))) float float4v;

__device__ __forceinline__ uint16_t f32_to_bf16_rne(float f) {
    union { float f; uint32_t u; } v; v.f = f;
    uint32_t u = v.u;
    return (uint16_t)((u + 0x7FFFu + ((u >> 16) & 1u)) >> 16);
}

// prep: blocks [0,16384): transpose+convert the 4 weights, [E][R][C] f32 -> [E][C][R] bf16.
//       blocks [16384,32768): straight fp32->bf16 convert of x (8 elems/thread, exact cover).
__global__ __launch_bounds__(256) void prep_all(
    const float* __restrict__ x,
    const float* __restrict__ i0, const float* __restrict__ i1,
    const float* __restrict__ i2, const float* __restrict__ i3,
    uint16_t* __restrict__ xb,
    uint16_t* __restrict__ o0, uint16_t* __restrict__ o1,
    uint16_t* __restrict__ o2, uint16_t* __restrict__ o3) {
    __shared__ float tile[32][33];
    int bx = blockIdx.x;
    if (bx >= 16384) {
        // x convert: 16384 blocks * 256 threads * 8 = 33,554,432 = E*T*H
        size_t idx = ((size_t)(bx - 16384) * 256 + threadIdx.x) * 8;
        float4 v0 = *(const float4*)(x + idx);
        float4 v1 = *(const float4*)(x + idx + 4);
        short8 s;
        s[0] = (short)f32_to_bf16_rne(v0.x);
        s[1] = (short)f32_to_bf16_rne(v0.y);
        s[2] = (short)f32_to_bf16_rne(v0.z);
        s[3] = (short)f32_to_bf16_rne(v0.w);
        s[4] = (short)f32_to_bf16_rne(v1.x);
        s[5] = (short)f32_to_bf16_rne(v1.y);
        s[6] = (short)f32_to_bf16_rne(v1.z);
        s[7] = (short)f32_to_bf16_rne(v1.w);
        *(short8*)(xb + idx) = s;
        return;
    }
    int w = bx >> 12;
    int t = bx & 4095;
    int e = t >> 9;
    int t2 = t & 511;
    const float* in = (w == 0) ? i0 : (w == 1) ? i1 : (w == 2) ? i2 : i3;
    uint16_t* out = (w == 0) ? o0 : (w == 1) ? o1 : (w == 2) ? o2 : o3;
    int R = (w & 1) ? 512 : 1024;      // w1,w3 are [H,I]; w2,w4 are [I,H]
    int C = (w & 1) ? 1024 : 512;
    int tilesX = C >> 5;               // 16 or 32
    int cx = t2 & (tilesX - 1);
    int ry = t2 / tilesX;
    int r0 = ry * 32, c0 = cx * 32;
    const float* src = in + (size_t)e * R * C;
    uint16_t* dst = out + (size_t)e * R * C;
    int tx = threadIdx.x & 31;
    int ty = threadIdx.x >> 5;  // 0..7
#pragma unroll
    for (int j = 0; j < 32; j += 8)
        tile[ty + j][tx] = src[(size_t)(r0 + ty + j) * C + (c0 + tx)];
    __syncthreads();
#pragma unroll
    for (int j = 0; j < 32; j += 8)
        dst[(size_t)(c0 + ty + j) * R + (r0 + tx)] = f32_to_bf16_rne(tile[tx][ty + j]);
}

__device__ __forceinline__ void storeC(float* p, float v) { *p = v; }
__device__ __forceinline__ void storeC(uint16_t* p, float v) { *p = f32_to_bf16_rne(v); }

// C[e][M][N] = A[e][M][K] * B[e][N][K]^T, A and B bf16 K-contiguous.
// 128x128 tile, BK=64, 4 waves (2x2), each wave 64x64 = 4x4 MFMA 16x16x32 tiles.
// Ping-pong double-buffered LDS: stage tile t+1 via global_load_lds BEFORE computing
// tile t; single barrier per K-step -> the vmcnt drain overlaps the whole compute phase.
// LDS slot swizzle kb' = kb ^ (row&7) keeps fragment ds_read_b128 conflict-free.
// 1D grid with XCD-chunked bijective swizzle: each XCD gets one expert's contiguous
// tile range (x-fastest) -> B panel resident in its private L2, A panels hot on re-read.
template <typename OutT>
__global__ __launch_bounds__(256, 2) void gemm_tn(
    const uint16_t* __restrict__ A,
    const uint16_t* __restrict__ B,
    OutT* __restrict__ C,
    int M, int N, int K)
{
    __shared__ __align__(16) uint16_t As[2][BM * BK];   // 2 x 16 KiB
    __shared__ __align__(16) uint16_t Bs[2][BN * BK];   // 2 x 16 KiB

    const int tid  = threadIdx.x;
    const int lane = tid & 63;
    const int wave = tid >> 6;          // 0..3
    const int wr = wave >> 1, wc = wave & 1;
    const int frow = lane & 15;
    const int quad = lane >> 4;
    const int xm = frow & 7;            // fragment-read xor mask

    // decode swizzled 1D block id  (gridDim.x = gx*32*8, divisible by 8)
    const int gxs = (N == 512) ? 2 : 3; // gx = N/BN is 4 or 8
    int id = blockIdx.x;
    int chunk = gridDim.x >> 3;
    int id2 = (id & 7) * chunk + (id >> 3);
    int bxi = id2 & ((1 << gxs) - 1);
    int rest = id2 >> gxs;
    int byi = rest & 31;                // gy = M/BM = 4096/128 = 32
    int e   = rest >> 5;
    const int bm = byi * BM;
    const int bn = bxi * BN;

    // staging map: thread t covers LDS 16B slot (row = t>>3 + 32*i, slot = t&7);
    // global source block kb = (t&7) ^ (row&7)
    const int srow = tid >> 3;                     // 0..31
    const int skb  = (tid & 7) ^ (srow & 7);
    const uint16_t* Ag = A + (size_t)e * M * K + (size_t)(bm + srow) * K + skb * 8;
    const uint16_t* Bg = B + (size_t)e * N * K + (size_t)(bn + srow) * K + skb * 8;

    float4v acc[4][4];
#pragma unroll
    for (int i = 0; i < 4; ++i)
#pragma unroll
        for (int j = 0; j < 4; ++j)
            acc[i][j] = (float4v){0.f, 0.f, 0.f, 0.f};

    const int ldsoff = wave * 1024;

    auto stage = [&](int buf, int k0) {
        char* asb = (char*)As[buf];
        char* bsb = (char*)Bs[buf];
#pragma unroll
        for (int i = 0; i < 4; ++i) {
            __builtin_amdgcn_global_load_lds(
                (const __attribute__((address_space(1))) void*)(Ag + k0 + (size_t)i * 32 * K),
                (__attribute__((address_space(3))) void*)(asb + i * 4096 + ldsoff),
                16, 0, 0);
            __builtin_amdgcn_global_load_lds(
                (const __attribute__((address_space(1))) void*)(Bg + k0 + (size_t)i * 32 * K),
                (__attribute__((address_space(3))) void*)(bsb + i * 4096 + ldsoff),
                16, 0, 0);
        }
    };

    stage(0, 0);                         // prologue: tile 0 -> buf 0
    const int nk = K / BK;
    int cur = 0;
    for (int t = 0; t < nk; ++t) {
        // barrier (implicit vmcnt(0)) : buf[cur] staged & everyone done reading buf[cur^1]
        __syncthreads();
        if (t + 1 < nk) stage(cur ^ 1, (t + 1) * BK);   // prefetch overlaps compute below
        char* asb = (char*)As[cur];
        char* bsb = (char*)Bs[cur];
#pragma unroll
        for (int s = 0; s < 2; ++s) {
            short8 a[4], b[4];
            const int kb = ((s * 4 + quad) ^ xm) * 16;  // swizzled byte slot
#pragma unroll
            for (int f = 0; f < 4; ++f) {
                a[f] = *(const short8*)(asb + (wr * 64 + f * 16 + frow) * 128 + kb);
                b[f] = *(const short8*)(bsb + (wc * 64 + f * 16 + frow) * 128 + kb);
            }
#pragma unroll
            for (int i = 0; i < 4; ++i)
#pragma unroll
                for (int j = 0; j < 4; ++j)
                    acc[i][j] = __builtin_amdgcn_mfma_f32_16x16x32_bf16(a[i], b[j], acc[i][j], 0, 0, 0);
        }
        cur ^= 1;
    }

    OutT* Ce = C + (size_t)e * M * N;
#pragma unroll
    for (int i = 0; i < 4; ++i) {
        int row0 = bm + wr * 64 + i * 16 + quad * 4;
#pragma unroll
        for (int j = 0; j < 4; ++j) {
            int col = bn + wc * 64 + j * 16 + frow;
#pragma unroll
            for (int r = 0; r < 4; ++r)
                storeC(&Ce[(size_t)(row0 + r) * N + col], acc[i][j][r]);
        }
    }
}

extern "C" void kernel_launch(void* const* d_in, const int* in_sizes, int n_in,
                              void* d_out, int out_size, void* d_ws, size_t ws_size,
                              hipStream_t stream) {
    const float* x  = (const float*)d_in[0];
    const float* w1 = (const float*)d_in[1];
    const float* w2 = (const float*)d_in[2];
    const float* w3 = (const float*)d_in[3];
    const float* w4 = (const float*)d_in[4];
    float* out = (float*)d_out;

    const int E = 8, T = 4096, H = 1024, I = 512;

    char* p = (char*)d_ws;
    uint16_t* w1b = (uint16_t*)p; p += (size_t)E * H * I * 2;   // 8 MiB, [E][I][H]
    uint16_t* w2b = (uint16_t*)p; p += (size_t)E * H * I * 2;   //        [E][H][I]
    uint16_t* w3b = (uint16_t*)p; p += (size_t)E * H * I * 2;
    uint16_t* w4b = (uint16_t*)p; p += (size_t)E * H * I * 2;
    uint16_t* h1  = (uint16_t*)p; p += (size_t)E * T * I * 2;   // 32 MiB
    uint16_t* h2  = (uint16_t*)p; p += (size_t)E * T * H * 2;   // 64 MiB
    uint16_t* h3  = h1;  // h1 dead once gemm3 runs
    uint16_t* xb  = h2;  // bf16 x aliases h2: dead before gemm2 writes h2

    // prep: 4*8*512 weight-transpose tiles + 16384 x-convert blocks, one launch
    prep_all<<<dim3(4 * 8 * 512 + 16384), dim3(256), 0, stream>>>(
        x, w1, w2, w3, w4, xb, w1b, w2b, w3b, w4b);

    // h1 = x @ w1          [T,H]x[H,I] -> [T,I]
    gemm_tn<uint16_t><<<dim3((I / BN) * 32 * E), dim3(256), 0, stream>>>(xb, w1b, h1, T, I, H);
    // h2 = h1 @ w2         [T,I]x[I,H] -> [T,H]
    gemm_tn<uint16_t><<<dim3((H / BN) * 32 * E), dim3(256), 0, stream>>>(h1, w2b, h2, T, H, I);
    // h3 = h2 @ w3         [T,H]x[H,I] -> [T,I]
    gemm_tn<uint16_t><<<dim3((I / BN) * 32 * E), dim3(256), 0, stream>>>(h2, w3b, h3, T, I, H);
    // out = h3 @ w4        [T,I]x[I,H] -> [T,H], fp32 out
    gemm_tn<float><<<dim3((H / BN) * 32 * E), dim3(256), 0, stream>>>(h3, w4b, out, T, H, I);
}